// Round 20
// baseline (201.841 us; speedup 1.0000x reference)
//
#include <hip/hip_runtime.h>

#define NROW 8192
#define INF  512
#define OUTF 256
#define M_ELEM (NROW * OUTF)   // 2,097,152 f32 per output matrix
#define NSTEP 32               // K-steps of 256

typedef __bf16 v8bf __attribute__((ext_vector_type(8)));
typedef __bf16 v4bf __attribute__((ext_vector_type(4)));
typedef float  v4f  __attribute__((ext_vector_type(4)));

__device__ __forceinline__ v8bf cvt_bf8(v4f u0, v4f u1) {
  v8bf v;
  v[0]=(__bf16)u0[0]; v[1]=(__bf16)u0[1]; v[2]=(__bf16)u0[2]; v[3]=(__bf16)u0[3];
  v[4]=(__bf16)u1[0]; v[5]=(__bf16)u1[1]; v[6]=(__bf16)u1[2]; v[7]=(__bf16)u1[3];
  return v;
}

// forced loads: issued exactly where written, dest regs held until consumed.
__device__ __forceinline__ v4f gload4f(const void* p) {
  v4f r;
  asm volatile("global_load_dwordx4 %0, %1, off" : "=v"(r) : "v"(p) : "memory");
  return r;
}
__device__ __forceinline__ v8bf gload8bf(const void* p) {
  v8bf r;
  asm volatile("global_load_dwordx4 %0, %1, off" : "=v"(r) : "v"(p) : "memory");
  return r;
}

// ---------------------------------------------------------------------------
// Kernel A: seq = feat @ W^T, bf16 MFMA, output in B-fragment-packed layout:
//   elem(m,o) -> (((m>>5)*16 + (o>>4))*64 + ((m>>3)&3)*16 + (o&15))*8 + (m&7)
// ---------------------------------------------------------------------------
__global__ __launch_bounds__(256) void seq_fts_kernel(
    const float* __restrict__ feat, const float* __restrict__ W,
    __bf16* __restrict__ Bp) {
  const int tid  = threadIdx.x;
  const int lane = tid & 63, w = tid >> 6;
  const int llo  = lane & 15, lhi = lane >> 4;
  const int row0 = blockIdx.x * 64;
  const int col0 = w * 64;

  v4f acc[4][4] = {};
#pragma unroll 1
  for (int kb = 0; kb < INF / 32; ++kb) {
    const int kofs = kb * 32 + lhi * 8;
    v8bf a[4], b[4];
#pragma unroll
    for (int i = 0; i < 4; ++i) {
      const float* p = feat + (size_t)(row0 + i * 16 + llo) * INF + kofs;
      a[i] = cvt_bf8(*(const v4f*)p, *(const v4f*)(p + 4));
    }
#pragma unroll
    for (int i = 0; i < 4; ++i) {
      const float* p = W + (size_t)(col0 + i * 16 + llo) * INF + kofs;
      b[i] = cvt_bf8(*(const v4f*)p, *(const v4f*)(p + 4));
    }
#pragma unroll
    for (int ri = 0; ri < 4; ++ri)
#pragma unroll
      for (int ci = 0; ci < 4; ++ci)
        acc[ri][ci] = __builtin_amdgcn_mfma_f32_16x16x32_bf16(
            a[ri], b[ci], acc[ri][ci], 0, 0, 0);
  }
#pragma unroll
  for (int ri = 0; ri < 4; ++ri)
#pragma unroll
    for (int ci = 0; ci < 4; ++ci) {
      const int mf = row0 + ri * 16 + lhi * 4;
      const int o  = col0 + ci * 16 + llo;
      size_t e = (((size_t)(mf >> 5) * 16 + (o >> 4)) * 64 +
                  ((mf >> 3) & 3) * 16 + (o & 15)) * 8 + (mf & 7);
      v4bf v;
      v[0] = (__bf16)acc[ri][ci][0]; v[1] = (__bf16)acc[ri][ci][1];
      v[2] = (__bf16)acc[ri][ci][2]; v[3] = (__bf16)acc[ri][ci][3];
      *(v4bf*)(Bp + e) = v;
    }
}

// ---------------------------------------------------------------------------
// Kernel B: out = prelu(adj @ seq + bias).
// R17 geometry; loads FORCED via inline-asm (compiler cannot split/sink them
// -- R19 proved sched_barrier alone is defeated: VGPR=100 vs the ~160 live
// set). Manual counted vmcnt: per step issue 16 B loads then 8 A loads;
// vmcnt(8) = all B landed, A(t+1) stays in flight across the WHOLE compute
// phase; vmcnt(0) only at step end (A landed by then; ~free). One raw
// barrier/step. XOR-swizzled LDS via key ((r&15)<<1)|((r>>3)&1).
// ---------------------------------------------------------------------------
__global__ __launch_bounds__(512, 1) void gcn_agg_kernel(
    const float* __restrict__ adjA, const float* __restrict__ adjB,
    const __bf16* __restrict__ Bp, const float* __restrict__ bias,
    const float* __restrict__ prelu_a, float* __restrict__ out) {
  const int tid  = threadIdx.x;
  const int lane = tid & 63, w = tid >> 6;   // wave w -> cols [w*32, w*32+32)
  const int llo  = lane & 15, lhi = lane >> 4;
  const int row0 = blockIdx.x * 64;
  const int z    = blockIdx.y;
  const float* __restrict__ adj = z ? adjB : adjA;

  __shared__ __align__(16) char LdsA[2][65536];   // 2 x (64 rows x 1 KB)

  v4f acc[4][2] = {};        // 32 VGPR
  v4f  areg[8];              // 32 VGPR, asm-held
  v8bf b[8][2];              // 64 VGPR, asm-held

  // A row i, step t: abase + i*32 KB + t*1 KB (1 KB contiguous extent/row)
  const char* abase = (const char*)(adj + (size_t)(row0 + w * 8) * NROW)
                      + (size_t)lane * 16;
  // B (t,g,ci): bbase + ((t*8+g)*16+ci)*1 KB
  const char* bbase = (const char*)(Bp + ((size_t)(w * 2) * 64 + lane) * 8);

  auto issue_a = [&](int t) {
#pragma unroll
    for (int i = 0; i < 8; ++i)
      areg[i] = gload4f(abase + (size_t)i * (NROW * 4) + (size_t)t * 1024);
  };
  auto issue_b = [&](int t) {
#pragma unroll
    for (int g = 0; g < 8; ++g)
#pragma unroll
      for (int ci = 0; ci < 2; ++ci)
        b[g][ci] = gload8bf(bbase + ((size_t)(t * 8 + g) * 16 + ci) * 1024);
  };
  auto write_a = [&](int buf) {
#pragma unroll
    for (int i = 0; i < 8; ++i) {
      const int r   = w * 8 + i;
      const int key = ((r & 15) << 1) | ((r >> 3) & 1);
      *(v4f*)(&LdsA[buf][r * 1024 + ((lane ^ key) << 4)]) = areg[i];
    }
  };
  auto compute_g = [&](int buf, int kg) {
    const char* ab = &LdsA[buf][0];
    v8bf af[4];
#pragma unroll
    for (int rt = 0; rt < 4; ++rt) {
      const int r   = rt * 16 + llo;
      const int key = ((r & 15) << 1) | ((r >> 3) & 1);
      const char* base = ab + r * 1024;
      v4f u0 = *(const v4f*)(base + (((kg * 8 + lhi * 2    ) ^ key) << 4));
      v4f u1 = *(const v4f*)(base + (((kg * 8 + lhi * 2 + 1) ^ key) << 4));
      af[rt] = cvt_bf8(u0, u1);
    }
#pragma unroll
    for (int ci = 0; ci < 2; ++ci)
#pragma unroll
      for (int rt = 0; rt < 4; ++rt)
        acc[rt][ci] = __builtin_amdgcn_mfma_f32_16x16x32_bf16(
            af[rt], b[kg][ci], acc[rt][ci], 0, 0, 0);
  };

  // prologue: A(0) -> LDS[0]
  issue_a(0);
  asm volatile("s_waitcnt vmcnt(0)" ::: "memory");
  __builtin_amdgcn_sched_barrier(0);
  write_a(0);
  asm volatile("s_waitcnt lgkmcnt(0)" ::: "memory");
  __builtin_amdgcn_sched_barrier(0);
  __builtin_amdgcn_s_barrier();

#pragma unroll 1
  for (int t = 0; t < NSTEP; ++t) {
    issue_b(t);                                   // 16 loads, oldest in FIFO
    const int tn = (t + 1 < NSTEP) ? t + 1 : t;   // clamp: constant FIFO math
    issue_a(tn);                                  // 8 loads, newest in FIFO
    // all B landed; A(t+1) stays in flight through the whole compute phase
    asm volatile("s_waitcnt vmcnt(8)" ::: "memory");
    __builtin_amdgcn_sched_barrier(0);
#pragma unroll
    for (int kg = 0; kg < 8; ++kg)
      compute_g(t & 1, kg);
    __builtin_amdgcn_sched_barrier(0);
    asm volatile("s_waitcnt vmcnt(0)" ::: "memory");  // A(t+1) landed (~free)
    __builtin_amdgcn_sched_barrier(0);
    if (t + 1 < NSTEP) {
      write_a((t + 1) & 1);
      asm volatile("s_waitcnt lgkmcnt(0)" ::: "memory");
      __builtin_amdgcn_sched_barrier(0);
    }
    __builtin_amdgcn_s_barrier();
  }
  asm volatile("s_waitcnt vmcnt(0)" ::: "memory");    // retire dangling loads

  // epilogue: bias + prelu, direct store
  const float slope = prelu_a[0];
  float* __restrict__ outp = out + (size_t)z * M_ELEM;
#pragma unroll
  for (int ci = 0; ci < 2; ++ci) {
    const int o  = w * 32 + ci * 16 + llo;
    const float bs = bias[o];
#pragma unroll
    for (int rt = 0; rt < 4; ++rt) {
      const int m = row0 + rt * 16 + lhi * 4;
#pragma unroll
      for (int r = 0; r < 4; ++r) {
        float v = acc[rt][ci][r] + bs;
        outp[(size_t)(m + r) * OUTF + o] = v >= 0.f ? v : slope * v;
      }
    }
  }
}

extern "C" void kernel_launch(void* const* d_in, const int* in_sizes, int n_in,
                              void* d_out, int out_size, void* d_ws, size_t ws_size,
                              hipStream_t stream) {
  const float* feat = (const float*)d_in[0];
  const float* adj  = (const float*)d_in[1];
  const float* aug  = (const float*)d_in[2];
  const float* W    = (const float*)d_in[3];
  const float* bias = (const float*)d_in[4];
  const float* pa   = (const float*)d_in[5];
  float* out = (float*)d_out;
  __bf16* Bp = (__bf16*)d_ws;                    // 4 MB packed seq_fts

  seq_fts_kernel<<<dim3(NROW / 64), 256, 0, stream>>>(feat, W, Bp);
  gcn_agg_kernel<<<dim3(NROW / 64, 2), 512, 0, stream>>>(
      adj, aug, Bp, bias, pa, out);
}